// Round 6
// baseline (140.962 us; speedup 1.0000x reference)
//
#include <hip/hip_runtime.h>
#include <math.h>

// Problem constants (match reference)
#define BATCH    8192
#define FIELDS   32
#define DIM      32
#define NREG     6
#define EPS      1e-5f
#define NBLK     1024      // 8 batch rows per block

// ws layout (floats): [0..31] sum[f], [32..63] sumsq[f]  (zeroed via memsetAsync)

// Pass 1: per-field sum / sumsq over (batch, dim).
// Thread t: field f = t>>3 (fixed), float4 column vec = t&7, 8 batch rows.
// Each field is contained in one wave -> 8-lane shfl reduce, then one
// atomicAdd pair per (block, field).
__global__ __launch_bounds__(256) void irazor_stats_kernel(
        const int*   __restrict__ ids,    // [BATCH, FIELDS]
        const float* __restrict__ table,  // [VOCAB, DIM]
        float*       __restrict__ ws) {
    const int t   = threadIdx.x;
    const int blk = blockIdx.x;
    const int f   = t >> 3;
    const int vec = t & 7;

    float s = 0.f, sq = 0.f;
    #pragma unroll
    for (int i = 0; i < 8; ++i) {
        const int id = ids[(blk * 8 + i) * FIELDS + f];
        const float4 v = *reinterpret_cast<const float4*>(
            table + (size_t)id * DIM + vec * 4);
        s  += v.x + v.y + v.z + v.w;
        sq += v.x * v.x + v.y * v.y + v.z * v.z + v.w * v.w;
    }

    #pragma unroll
    for (int off = 1; off < 8; off <<= 1) {
        s  += __shfl_xor(s, off);
        sq += __shfl_xor(sq, off);
    }
    if (vec == 0) {
        atomicAdd(&ws[f], s);
        atomicAdd(&ws[32 + f], sq);
    }
}

// Pass 2: normalize + region-softmax scale, coalesced float4 store.
// Table re-gather hits L2/L3 (resident after pass 1).
__global__ __launch_bounds__(256) void irazor_out_kernel(
        const int*   __restrict__ ids,
        const float* __restrict__ table,
        const float* __restrict__ frw,    // [FIELDS, NREG]
        const float* __restrict__ mask,   // [NREG, DIM]
        const float* __restrict__ ws,
        float*       __restrict__ out) {  // [BATCH, FIELDS, DIM]
    const int t   = threadIdx.x;
    const int blk = blockIdx.x;

    // coef[f][d] = softmax(frw[f,:]) . mask[:,d]  (recomputed per block, cheap)
    __shared__ float scoef[FIELDS][DIM];
    {
        const int f2 = t & 31;
        const int q  = t >> 5;          // 0..7 -> 4 dims each
        float w[NREG]; float m = -1e30f;
        #pragma unroll
        for (int r = 0; r < NREG; ++r) { w[r] = frw[f2 * NREG + r]; m = fmaxf(m, w[r]); }
        float ssum = 0.f;
        #pragma unroll
        for (int r = 0; r < NREG; ++r) { w[r] = __expf(w[r] - m); ssum += w[r]; }
        const float inv = 1.f / ssum;
        #pragma unroll
        for (int dd = 0; dd < 4; ++dd) {
            const int d = q * 4 + dd;
            float c = 0.f;
            #pragma unroll
            for (int r = 0; r < NREG; ++r) c += w[r] * mask[r * DIM + d];
            scoef[f2][d] = c * inv;
        }
    }
    __syncthreads();

    const int f   = t >> 3;
    const int vec = t & 7;
    const float invN = 1.f / (float)(BATCH * DIM);
    const float mean = ws[f] * invN;
    const float var  = ws[32 + f] * invN - mean * mean;
    const float istd = rsqrtf(var + EPS);
    const float4 c = *reinterpret_cast<const float4*>(&scoef[f][vec * 4]);

    float4* __restrict__ out4 = reinterpret_cast<float4*>(out);
    #pragma unroll
    for (int i = 0; i < 8; ++i) {
        const int id = ids[(blk * 8 + i) * FIELDS + f];
        const float4 v = *reinterpret_cast<const float4*>(
            table + (size_t)id * DIM + vec * 4);
        float4 o;
        o.x = (v.x - mean) * istd * c.x;
        o.y = (v.y - mean) * istd * c.y;
        o.z = (v.z - mean) * istd * c.z;
        o.w = (v.w - mean) * istd * c.w;
        out4[(size_t)blk * 2048 + (size_t)i * 256 + t] = o;
    }
}

extern "C" void kernel_launch(void* const* d_in, const int* in_sizes, int n_in,
                              void* d_out, int out_size, void* d_ws, size_t ws_size,
                              hipStream_t stream) {
    const int*   ids   = (const int*)d_in[0];    // [BATCH, FIELDS] int32
    const float* table = (const float*)d_in[1];  // [VOCAB, DIM] f32
    const float* frw   = (const float*)d_in[2];  // [FIELDS, NREG, 1] f32
    const float* mask  = (const float*)d_in[3];  // [NREG, DIM] f32
    float*       out   = (float*)d_out;
    float*       ws    = (float*)d_ws;

    hipMemsetAsync(ws, 0, 64 * sizeof(float), stream);
    irazor_stats_kernel<<<NBLK, 256, 0, stream>>>(ids, table, ws);
    irazor_out_kernel<<<NBLK, 256, 0, stream>>>(ids, table, frw, mask, ws, out);
}

// Round 16
// 100.141 us; speedup vs baseline: 1.4076x; 1.4076x over previous
//
#include <hip/hip_runtime.h>
#include <math.h>

// Problem constants (match reference)
#define BATCH    8192
#define FIELDS   32
#define DIM      32
#define NREG     6
#define EPS      1e-5f
#define NBLKA    4096          // stats/out blocks: 2 batch rows per block
#define PBASE    64            // ws float offset of per-block partials

// ws layout (floats):
//   [0..31]   final sum[f]      (written by reduce kernel)
//   [32..63]  final sumsq[f]
//   [PBASE + slot*NBLKA + blk]  per-block partials, slot = f (sum) or 32+f (sumsq)
// No atomics, no memset: every word is written before it is read.

// Pass A: per-block per-field partial sum/sumsq. 2 rows per block.
// Thread t: field f = t>>3, float4 column vec = t&7.
__global__ __launch_bounds__(256) void irazor_stats_kernel(
        const int*   __restrict__ ids,    // [BATCH, FIELDS]
        const float* __restrict__ table,  // [VOCAB, DIM]
        float*       __restrict__ ws) {
    const int t   = threadIdx.x;
    const int blk = blockIdx.x;
    const int f   = t >> 3;
    const int vec = t & 7;

    float s = 0.f, sq = 0.f;
    #pragma unroll
    for (int i = 0; i < 2; ++i) {
        const int id = ids[(blk * 2 + i) * FIELDS + f];
        const float4 v = *reinterpret_cast<const float4*>(
            table + (size_t)id * DIM + vec * 4);
        s  += v.x + v.y + v.z + v.w;
        sq += v.x * v.x + v.y * v.y + v.z * v.z + v.w * v.w;
    }

    #pragma unroll
    for (int off = 1; off < 8; off <<= 1) {
        s  += __shfl_xor(s, off);
        sq += __shfl_xor(sq, off);
    }
    if (vec == 0) {                       // threads 0,8,...,248: one per field
        ws[PBASE + f * NBLKA + blk]        = s;
        ws[PBASE + (32 + f) * NBLKA + blk] = sq;
    }
}

// Pass B: one block per stat slot; contiguous coalesced reduction of 4096 floats.
__global__ __launch_bounds__(256) void irazor_reduce_kernel(float* __restrict__ ws) {
    const int slot = blockIdx.x;          // 0..63
    const int t    = threadIdx.x;
    const float* __restrict__ p = ws + PBASE + (size_t)slot * NBLKA;
    float acc = 0.f;
    #pragma unroll
    for (int i = 0; i < NBLKA / 256; ++i) acc += p[i * 256 + t];
    #pragma unroll
    for (int off = 1; off < 64; off <<= 1) acc += __shfl_xor(acc, off);
    __shared__ float l[4];
    if ((t & 63) == 0) l[t >> 6] = acc;
    __syncthreads();
    if (t == 0) ws[slot] = l[0] + l[1] + l[2] + l[3];
}

// Pass C: normalize + region-softmax scale, coalesced float4 store.
__global__ __launch_bounds__(256) void irazor_out_kernel(
        const int*   __restrict__ ids,
        const float* __restrict__ table,
        const float* __restrict__ frw,    // [FIELDS, NREG]
        const float* __restrict__ mask,   // [NREG, DIM]
        const float* __restrict__ ws,
        float*       __restrict__ out) {  // [BATCH, FIELDS, DIM]
    const int t   = threadIdx.x;
    const int blk = blockIdx.x;

    // coef[f][d] = softmax(frw[f,:]) . mask[:,d]  (recomputed per block, cheap)
    __shared__ float scoef[FIELDS][DIM];
    {
        const int f2 = t & 31;
        const int q  = t >> 5;            // 0..7 -> 4 dims each
        float w[NREG]; float m = -1e30f;
        #pragma unroll
        for (int r = 0; r < NREG; ++r) { w[r] = frw[f2 * NREG + r]; m = fmaxf(m, w[r]); }
        float ssum = 0.f;
        #pragma unroll
        for (int r = 0; r < NREG; ++r) { w[r] = __expf(w[r] - m); ssum += w[r]; }
        const float inv = 1.f / ssum;
        #pragma unroll
        for (int dd = 0; dd < 4; ++dd) {
            const int d = q * 4 + dd;
            float c = 0.f;
            #pragma unroll
            for (int r = 0; r < NREG; ++r) c += w[r] * mask[r * DIM + d];
            scoef[f2][d] = c * inv;
        }
    }
    __syncthreads();

    const int f   = t >> 3;
    const int vec = t & 7;
    const float invN = 1.f / (float)(BATCH * DIM);
    const float mean = ws[f] * invN;
    const float var  = ws[32 + f] * invN - mean * mean;
    const float istd = rsqrtf(var + EPS);
    const float4 c = *reinterpret_cast<const float4*>(&scoef[f][vec * 4]);

    float4* __restrict__ out4 = reinterpret_cast<float4*>(out);
    #pragma unroll
    for (int i = 0; i < 2; ++i) {
        const int id = ids[(blk * 2 + i) * FIELDS + f];
        const float4 v = *reinterpret_cast<const float4*>(
            table + (size_t)id * DIM + vec * 4);
        float4 o;
        o.x = (v.x - mean) * istd * c.x;
        o.y = (v.y - mean) * istd * c.y;
        o.z = (v.z - mean) * istd * c.z;
        o.w = (v.w - mean) * istd * c.w;
        out4[(size_t)blk * 512 + (size_t)i * 256 + t] = o;
    }
}

extern "C" void kernel_launch(void* const* d_in, const int* in_sizes, int n_in,
                              void* d_out, int out_size, void* d_ws, size_t ws_size,
                              hipStream_t stream) {
    const int*   ids   = (const int*)d_in[0];    // [BATCH, FIELDS] int32
    const float* table = (const float*)d_in[1];  // [VOCAB, DIM] f32
    const float* frw   = (const float*)d_in[2];  // [FIELDS, NREG, 1] f32
    const float* mask  = (const float*)d_in[3];  // [NREG, DIM] f32
    float*       out   = (float*)d_out;
    float*       ws    = (float*)d_ws;

    irazor_stats_kernel<<<NBLKA, 256, 0, stream>>>(ids, table, ws);
    irazor_reduce_kernel<<<64, 256, 0, stream>>>(ws);
    irazor_out_kernel<<<NBLKA, 256, 0, stream>>>(ids, table, frw, mask, ws, out);
}